// Round 7
// baseline (864.332 us; speedup 1.0000x reference)
//
#include <hip/hip_runtime.h>

// Problem constants
#define Bv    32
#define Lv    512
#define Hv    512
#define Fv    512
#define Tv    4096
#define Mv    (Bv*Lv)          // 16384 rows
#define NBINSv 256

// d_out layout (floats): out(B,T,H) | pit(B,L) | eng(B,L) | log_dur(B,L) | mel_len(B)
#define OUT_OFF 0
#define PIT_OFF (Bv*(size_t)Tv*Hv)              // 67108864
#define ENG_OFF (PIT_OFF + Mv)
#define DUR_OFF (ENG_OFF + Mv)
#define MEL_OFF (DUR_OFF + Mv)

typedef unsigned short ushort;
typedef unsigned char  uchar;
typedef __attribute__((ext_vector_type(8))) short   bf16x8;   // 8 bf16 in 4 VGPRs
typedef __attribute__((ext_vector_type(4))) float   f32x4;
typedef __attribute__((ext_vector_type(8))) unsigned short u16x8;

__device__ __forceinline__ float b2f(ushort u) {
    union { float f; unsigned u; } x; x.u = ((unsigned)u) << 16; return x.f;
}
__device__ __forceinline__ ushort f2b(float f) {
    union { float f; unsigned u; } x; x.f = f;
    unsigned r = x.u + 0x7fffu + ((x.u >> 16) & 1u);   // RNE
    return (ushort)(r >> 16);
}
// fp8 e4m3 (OCP) convert via HW packed-convert
__device__ __forceinline__ uchar f2e4(float f) {
    int r = __builtin_amdgcn_cvt_pk_fp8_f32(f, 0.f, 0, false);
    return (uchar)(r & 0xff);
}
__device__ __forceinline__ int pk4e4(float v0, float v1, float v2, float v3) {
    int r = __builtin_amdgcn_cvt_pk_fp8_f32(v0, v1, 0, false);
    r     = __builtin_amdgcn_cvt_pk_fp8_f32(v2, v3, r, true);
    return r;            // bytes [v0,v1,v2,v3] little-endian
}

#define GLL16(g, l) __builtin_amdgcn_global_load_lds( \
    (const __attribute__((address_space(1))) void*)(g), \
    (__attribute__((address_space(3))) void*)(l), 16, 0, 0)

// Struct-of-pointers kernel args for z-batched launches
template<int NZ> struct GArgs {
    const ushort* A[NZ];
    const ushort* W[NZ];
    const float*  bias[NZ];
    ushort*       C[NZ];
};
template<int NZ> struct GArgs8 {
    const uchar* A[NZ];
    const uchar* W[NZ];
    const float* bias[NZ];
    uchar*       C[NZ];
};
// Epilogue fusion args (RMS folds).  rss: conv1 row sum-of-squares accum
// (conv2 reads it to form inv inline).  ss2/sgw: conv2 rmslin partials.
struct EpiArgs {
    float* rss; float* ss2; float* sgw;
    const float* g2[3]; const float* wl[3];
};
struct TransArgs { const float* src[6]; const float* gs[6]; void* dst[6]; };

// ---------------------------------------------------------------------------
// bf16 MFMA GEMM, z-batched (proj1/proj2).  R0-proven structure: 128x128
// tile, BK=32, 256 thr = 4 waves, 16 KiB LDS -> ~3 blocks/CU.  T1 chunked
// XCD swizzle.  EPI 0: relu -> bf16 C.  EPI 3: per-z: z<2 relu+res -> FP8 C
// (feeds fp8 conv1); z==2 relu+res+pe+ee -> bf16 C (xob for regulate).
// ---------------------------------------------------------------------------
template<int NTAPS, int EPI, int NZ>
__global__ __launch_bounds__(256) void gemm_bf16_kernel(
    GArgs<NZ> ga, const float* __restrict__ res,
    const float* __restrict__ pe, const float* __restrict__ ee,
    const int* __restrict__ idxp, const int* __restrict__ idxe,
    const ushort* __restrict__ zp)
{
    constexpr int KTOT = NTAPS * 512;
    constexpr int GX   = Fv / 128;           // 4
    constexpr int GY   = Mv / 128;           // 128
    constexpr int NWG  = GX * GY * NZ;

    int lin = blockIdx.x + GX * (blockIdx.y + GY * blockIdx.z);
    lin = (lin & 7) * (NWG >> 3) + (lin >> 3);
    const int bx = lin & (GX - 1);
    const int by = (lin >> 2) & (GY - 1);
    const int z  = (NZ > 1) ? (lin / (GX * GY)) : 0;

    const ushort* __restrict__ A    = ga.A[z];
    const ushort* __restrict__ Bt   = ga.W[z];
    const float*  __restrict__ bias = ga.bias[z];
    ushort*       __restrict__ C    = ga.C[z];

    __shared__ ushort As[128 * 32];
    __shared__ ushort Bs[128 * 32];

    const int tid = threadIdx.x;
    const int n0 = bx * 128;
    const int m0 = by * 128;

    const int sar = tid >> 2;       // staging row
    const int sl  = tid & 3;        // staging 16B slot

    const int lane = tid & 63;
    const int w    = tid >> 6;
    const int wm   = (w & 1) * 64;
    const int wn   = (w >> 1) * 64;
    const int lr   = lane & 15;
    const int q    = lane >> 4;

    f32x4 acc[4][4];
    #pragma unroll
    for (int i = 0; i < 4; ++i)
        #pragma unroll
        for (int j = 0; j < 4; ++j) {
            f32x4 zz = {0.f, 0.f, 0.f, 0.f};
            acc[i][j] = zz;
        }

    for (int kt = 0; kt < NTAPS * 16; ++kt) {
        const int tap = (NTAPS == 3) ? (kt >> 4) : 0;
        const int kin = (NTAPS == 3) ? ((kt & 15) << 5) : (kt << 5);

        #pragma unroll
        for (int r = 0; r < 2; ++r) {
            const int row = sar + r * 64;
            const int m   = m0 + row;
            const int qg  = (sl - (row >> 1)) & 3;
            const ushort* asrc;
            if (NTAPS == 3) {
                const int l  = m & (Lv - 1);
                const int ls = l + tap - 1;
                asrc = ((unsigned)ls < (unsigned)Lv)
                     ? A + (size_t)(m + tap - 1) * 512 + kin + qg * 8
                     : zp;
            } else {
                asrc = A + (size_t)m * 512 + kin + qg * 8;
            }
            GLL16(asrc, &As[row * 32 + sl * 8]);
            const ushort* bsrc = Bt + (size_t)(n0 + row) * KTOT + tap * 512 + kin + qg * 8;
            GLL16(bsrc, &Bs[row * 32 + sl * 8]);
        }
        __syncthreads();

        bf16x8 af[4], bfr[4];
        #pragma unroll
        for (int i = 0; i < 4; ++i) {
            const int rm = wm + i * 16 + lr;
            af[i]  = *(const bf16x8*)&As[rm * 32 + (((q + (rm >> 1)) & 3) << 3)];
            const int rn = wn + i * 16 + lr;
            bfr[i] = *(const bf16x8*)&Bs[rn * 32 + (((q + (rn >> 1)) & 3) << 3)];
        }
        #pragma unroll
        for (int i = 0; i < 4; ++i)
            #pragma unroll
            for (int j = 0; j < 4; ++j)
                acc[i][j] = __builtin_amdgcn_mfma_f32_16x16x32_bf16(
                                af[i], bfr[j], acc[i][j], 0, 0, 0);
        __syncthreads();
    }

    // epilogue: C/D layout col = lane&15 (n), row = q*4 + reg
    uchar* C8 = (uchar*)C;
    #pragma unroll
    for (int i = 0; i < 4; ++i) {
        #pragma unroll
        for (int r = 0; r < 4; ++r) {
            const int m = m0 + wm + i * 16 + q * 4 + r;
            const size_t ro = (size_t)m * 512;
            int ip = 0, ie = 0;
            if (EPI == 3 && z == 2) { ip = idxp[m]; ie = idxe[m]; }
            #pragma unroll
            for (int j = 0; j < 4; ++j) {
                const int n = n0 + wn + j * 16 + lr;
                float v = acc[i][j][r] + bias[n];
                v = fmaxf(v, 0.f);
                if (EPI == 3) v += res[ro + n];
                if (EPI == 3 && z == 2)
                    v += pe[(size_t)ip * 512 + n] + ee[(size_t)ie * 512 + n];
                if (EPI == 3 && z < 2) C8[ro + n] = f2e4(v);
                else                   C[ro + n]  = f2b(v);
            }
        }
    }
}

// ---------------------------------------------------------------------------
// fp8 e4m3 MFMA GEMM, z-batched (conv1/conv2; NTAPS=3, KTOT=1536).
// Same 128x128/BK=32 skeleton; 8 KiB LDS; 2 GLL16 per thread-iter (vs 4).
// LDS 16B-slot swizzle: LDS slot s holds global slot s ^ ((row>>2)&1)
// (involution; pre-swizzled global source, same XOR on ds_read_b64 -> 2-way
// bank aliasing = free).  mfma_f32_16x16x32_fp8_fp8, frag = 8 fp8 = 1 long.
// EPI 4 (conv1): relu -> fp8 C + atomic row sum(v^2) -> rss.
// EPI 5 (conv2): v = relu(acc*inv(rss[m]) + bias); no C write; atomic row
//                sum(v^2) -> ss2, sum(v*g2[n]*wl[n]) -> sgw  (rmslin fold).
// ---------------------------------------------------------------------------
template<int EPI, int NZ>
__global__ __launch_bounds__(256) void gemm_fp8_kernel(
    GArgs8<NZ> ga, EpiArgs ea, const uchar* __restrict__ zp)
{
    constexpr int GX = 4, GY = 128, NWG = GX * GY * NZ;

    int lin = blockIdx.x + GX * (blockIdx.y + GY * blockIdx.z);
    lin = (lin & 7) * (NWG >> 3) + (lin >> 3);
    const int bx = lin & (GX - 1);
    const int by = (lin >> 2) & (GY - 1);
    const int z  = (NZ > 1) ? (lin / (GX * GY)) : 0;

    const uchar* __restrict__ A    = ga.A[z];
    const uchar* __restrict__ Bt   = ga.W[z];
    const float* __restrict__ bias = ga.bias[z];
    uchar*       __restrict__ C    = ga.C[z];

    __shared__ long Asl[512];                // 4 KiB
    __shared__ long Bsl[512];                // 4 KiB
    uchar* As = (uchar*)Asl;
    uchar* Bs = (uchar*)Bsl;

    const int tid = threadIdx.x;
    const int n0 = bx * 128;
    const int m0 = by * 128;

    const int sar = tid >> 1;       // staging row 0..127
    const int sl  = tid & 1;        // staging 16B slot

    const int lane = tid & 63;
    const int w    = tid >> 6;
    const int wm   = (w & 1) * 64;
    const int wn   = (w >> 1) * 64;
    const int lr   = lane & 15;
    const int q    = lane >> 4;

    f32x4 acc[4][4];
    #pragma unroll
    for (int i = 0; i < 4; ++i)
        #pragma unroll
        for (int j = 0; j < 4; ++j) {
            f32x4 zz = {0.f, 0.f, 0.f, 0.f};
            acc[i][j] = zz;
        }

    const int gs = (sl ^ ((sar >> 2) & 1)) << 4;   // pre-swizzled 16B slot
    for (int kt = 0; kt < 48; ++kt) {
        const int tap = kt >> 4;
        const int kin = (kt & 15) << 5;            // bytes within tap
        {
            const int m  = m0 + sar;
            const int ls = (m & (Lv - 1)) + tap - 1;
            const uchar* asrc = ((unsigned)ls < (unsigned)Lv)
                ? A + (size_t)(m + tap - 1) * 512 + kin + gs
                : zp;
            GLL16(asrc, &As[sar * 32 + sl * 16]);
            const uchar* bsrc = Bt + (size_t)(n0 + sar) * 1536 + tap * 512 + kin + gs;
            GLL16(bsrc, &Bs[sar * 32 + sl * 16]);
        }
        __syncthreads();

        long af[4], bf[4];
        #pragma unroll
        for (int i = 0; i < 4; ++i) {
            const int rm = wm + i * 16 + lr;
            af[i] = *(const long*)&As[rm * 32 + (((q >> 1) ^ ((rm >> 2) & 1)) << 4) + ((q & 1) << 3)];
            const int rn = wn + i * 16 + lr;
            bf[i] = *(const long*)&Bs[rn * 32 + (((q >> 1) ^ ((rn >> 2) & 1)) << 4) + ((q & 1) << 3)];
        }
        #pragma unroll
        for (int i = 0; i < 4; ++i)
            #pragma unroll
            for (int j = 0; j < 4; ++j)
                acc[i][j] = __builtin_amdgcn_mfma_f32_16x16x32_fp8_fp8(
                                af[i], bf[j], acc[i][j], 0, 0, 0);
        __syncthreads();
    }

    // epilogue
    #pragma unroll
    for (int i = 0; i < 4; ++i) {
        #pragma unroll
        for (int r = 0; r < 4; ++r) {
            const int m = m0 + wm + i * 16 + q * 4 + r;
            const size_t ro = (size_t)m * 512;
            float rowinv = 1.f;
            if (EPI == 5)
                rowinv = 1.f / (sqrtf(ea.rss[(size_t)z * Mv + m] * (1.f / 512.f)) + 1e-8f);
            float ssp = 0.f, sgwp = 0.f;
            #pragma unroll
            for (int j = 0; j < 4; ++j) {
                const int n = n0 + wn + j * 16 + lr;
                float v = (EPI == 5) ? (acc[i][j][r] * rowinv + bias[n])
                                     : (acc[i][j][r] + bias[n]);
                v = fmaxf(v, 0.f);
                if (EPI == 4) { C[ro + n] = f2e4(v); ssp += v * v; }
                else          { ssp += v * v; sgwp += v * ea.g2[z][n] * ea.wl[z][n]; }
            }
            #pragma unroll
            for (int mm = 1; mm < 16; mm <<= 1) {
                ssp += __shfl_xor(ssp, mm, 64);
                if (EPI == 5) sgwp += __shfl_xor(sgwp, mm, 64);
            }
            if (lr == 0) {
                if (EPI == 4) atomicAdd(&ea.rss[(size_t)z * Mv + m], ssp);
                else {
                    atomicAdd(&ea.ss2[(size_t)z * Mv + m], ssp);
                    atomicAdd(&ea.sgw[(size_t)z * Mv + m], sgwp);
                }
            }
        }
    }
}

// ---------------------------------------------------------------------------
// convert: y=0: x fp32 -> fp8 (conv1 dur input); y=1: emb fp32 -> bf16
// ---------------------------------------------------------------------------
__global__ __launch_bounds__(256) void convert_kernel(
    const float* __restrict__ x, const float* __restrict__ emb,
    uchar* __restrict__ xb8, ushort* __restrict__ eb)
{
    const size_t i = (size_t)blockIdx.x * 256 + threadIdx.x;
    if (blockIdx.y == 0) {
        const float4 a = ((const float4*)x)[2 * i];
        const float4 b = ((const float4*)x)[2 * i + 1];
        int2 o;
        o.x = pk4e4(a.x, a.y, a.z, a.w);
        o.y = pk4e4(b.x, b.y, b.z, b.w);
        ((int2*)xb8)[i] = o;
    } else {
        const float4 a = ((const float4*)emb)[2 * i];
        const float4 b = ((const float4*)emb)[2 * i + 1];
        u16x8 o;
        o[0] = f2b(a.x); o[1] = f2b(a.y); o[2] = f2b(a.z); o[3] = f2b(a.w);
        o[4] = f2b(b.x); o[5] = f2b(b.y); o[6] = f2b(b.z); o[7] = f2b(b.w);
        *(u16x8*)(eb + i * 8) = o;
    }
}

// ---------------------------------------------------------------------------
// Weight transpose+convert, z-batched: W[kk][n] fp32 -> Wt[n][kk].
// FP8 template flag; optional per-K-row scale gs (g1 fold into conv2 w).
// ---------------------------------------------------------------------------
template<int FP8>
__global__ __launch_bounds__(256) void transpose_kernel(TransArgs ta, int Ktot)
{
    const float* __restrict__ W  = ta.src[blockIdx.z];
    const float* __restrict__ gs = ta.gs[blockIdx.z];
    __shared__ float t[32][33];
    const int k0 = blockIdx.x * 32, n0 = blockIdx.y * 32;
    const int r = threadIdx.x >> 5, c = threadIdx.x & 31;
    #pragma unroll
    for (int rr = 0; rr < 4; ++rr) {
        const int kk = k0 + r + rr * 8;
        float v = W[(size_t)kk * 512 + n0 + c];
        if (gs) v *= gs[kk & 511];
        t[r + rr * 8][c] = v;
    }
    __syncthreads();
    #pragma unroll
    for (int rr = 0; rr < 4; ++rr) {
        const size_t o = (size_t)(n0 + r + rr * 8) * Ktot + k0 + c;
        if (FP8) ((uchar*)ta.dst[blockIdx.z])[o]  = f2e4(t[c][r + rr * 8]);
        else     ((ushort*)ta.dst[blockIdx.z])[o] = f2b(t[c][r + rr * 8]);
    }
}

// ---------------------------------------------------------------------------
// pred finalize: pred[i] = mask ? 0 : sgw[i]/(sqrt(ss2[i]/512)+eps) + bl[z]
// ---------------------------------------------------------------------------
__global__ __launch_bounds__(256) void pred_kernel(
    const float* __restrict__ ss2, const float* __restrict__ sgw,
    const unsigned char* __restrict__ mask,
    const float* __restrict__ bl0, const float* __restrict__ bl1,
    const float* __restrict__ bl2, float* __restrict__ predbase)
{
    const int i = blockIdx.x * 256 + threadIdx.x;
    const int zz = i >> 14;                  // Mv = 2^14
    const int row = i & (Mv - 1);
    const float bl = (zz == 0 ? bl0 : (zz == 1 ? bl1 : bl2))[0];
    const float inv = 1.f / (sqrtf(ss2[i] * (1.f / 512.f)) + 1e-8f);
    predbase[i] = mask[row] ? 0.f : (sgw[i] * inv + bl);
}

// ---------------------------------------------------------------------------
// searchsorted(bins, v, 'left') for pitch & energy targets
// ---------------------------------------------------------------------------
__global__ __launch_bounds__(256) void idx_kernel(
    const float* __restrict__ pt, const float* __restrict__ et,
    const float* __restrict__ pbins, const float* __restrict__ ebins,
    int* __restrict__ idxp, int* __restrict__ idxe)
{
    __shared__ float pb[NBINSv - 1], ebn[NBINSv - 1];
    const int tid = threadIdx.x;
    if (tid < NBINSv - 1) { pb[tid] = pbins[tid]; ebn[tid] = ebins[tid]; }
    __syncthreads();
    const int m = blockIdx.x * 256 + tid;
    const float pv = pt[m], ev = et[m];
    int lo = 0, hi = NBINSv - 1;
    while (lo < hi) { int mid = (lo + hi) >> 1; if (pb[mid] < pv) lo = mid + 1; else hi = mid; }
    idxp[m] = lo;
    lo = 0; hi = NBINSv - 1;
    while (lo < hi) { int mid = (lo + hi) >> 1; if (ebn[mid] < ev) lo = mid + 1; else hi = mid; }
    idxe[m] = lo;
}

// ---------------------------------------------------------------------------
// Merged cumsum + tmap: per batch, scan durations in LDS, emit mel_len and
// the regulate source map via LDS-resident binary searches (1 launch, no
// global cum buffer).
// ---------------------------------------------------------------------------
__global__ __launch_bounds__(512) void cumtmap_kernel(
    const int* __restrict__ dur, float* __restrict__ melout,
    int* __restrict__ tmap)
{
    __shared__ int s[Lv];
    const int b = blockIdx.x, tid = threadIdx.x;
    s[tid] = dur[b * Lv + tid];
    __syncthreads();
    for (int off = 1; off < Lv; off <<= 1) {
        int t = (tid >= off) ? s[tid - off] : 0;
        __syncthreads();
        s[tid] += t;
        __syncthreads();
    }
    const int mel = s[Lv - 1];
    if (tid == Lv - 1) melout[b] = (float)mel;
    for (int t = tid; t < Tv; t += Lv) {
        int lo = 0, hi = Lv;
        while (lo < hi) { int mid = (lo + hi) >> 1; if (s[mid] <= t) lo = mid + 1; else hi = mid; }
        tmap[b * Tv + t] = (t < mel) ? (b * Lv + min(lo, Lv - 1)) : -1;
    }
}

// ---------------------------------------------------------------------------
// Length regulate gather: out[bt,:] = tmap[bt] >= 0 ? xo[tmap[bt],:] : 0
// ---------------------------------------------------------------------------
__global__ __launch_bounds__(128) void regulate_kernel(
    const ushort* __restrict__ xo, const int* __restrict__ tmap,
    float* __restrict__ out)
{
    const int bt = blockIdx.x;
    const int src = tmap[bt];
    float4 v = make_float4(0.f, 0.f, 0.f, 0.f);
    if (src >= 0) {
        const ushort4 u = ((const ushort4*)(xo + (size_t)src * 512))[threadIdx.x];
        v.x = b2f(u.x); v.y = b2f(u.y); v.z = b2f(u.z); v.w = b2f(u.w);
    }
    ((float4*)(out + (size_t)bt * 512))[threadIdx.x] = v;
}

// ---------------------------------------------------------------------------
extern "C" void kernel_launch(void* const* d_in, const int* in_sizes, int n_in,
                              void* d_out, int out_size, void* d_ws, size_t ws_size,
                              hipStream_t stream)
{
    const float* x    = (const float*)d_in[0];
    const float* emb  = (const float*)d_in[1];
    const unsigned char* mask = (const unsigned char*)d_in[2];
    const int*   durt = (const int*)d_in[3];
    const float* pt   = (const float*)d_in[4];
    const float* et   = (const float*)d_in[5];
    const float* dw1 = (const float*)d_in[7],  *db1 = (const float*)d_in[8],
               * dg1 = (const float*)d_in[9],  *dw2 = (const float*)d_in[10],
               * db2 = (const float*)d_in[11], *dg2 = (const float*)d_in[12],
               * dwl = (const float*)d_in[13], *dbl = (const float*)d_in[14];
    const float* pw1 = (const float*)d_in[15], *pb1 = (const float*)d_in[16],
               * pg1 = (const float*)d_in[17], *pw2 = (const float*)d_in[18],
               * pb2 = (const float*)d_in[19], *pg2 = (const float*)d_in[20],
               * pwl = (const float*)d_in[21], *pbl = (const float*)d_in[22];
    const float* ew1 = (const float*)d_in[23], *eb1 = (const float*)d_in[24],
               * eg1 = (const float*)d_in[25], *ew2 = (const float*)d_in[26],
               * eb2 = (const float*)d_in[27], *eg2 = (const float*)d_in[28],
               * ewl = (const float*)d_in[29], *ebl = (const float*)d_in[30];
    const float* ppw1 = (const float*)d_in[31], *ppb1 = (const float*)d_in[32],
               * ppw2 = (const float*)d_in[33], *ppb2 = (const float*)d_in[34];
    const float* epw1 = (const float*)d_in[35], *epb1 = (const float*)d_in[36],
               * epw2 = (const float*)d_in[37], *epb2 = (const float*)d_in[38];
    const float* spw1 = (const float*)d_in[39], *spb1 = (const float*)d_in[40],
               * spw2 = (const float*)d_in[41], *spb2 = (const float*)d_in[42];
    const float* pbins = (const float*)d_in[43];
    const float* ebins = (const float*)d_in[44];
    const float* pemb  = (const float*)d_in[45];
    const float* eemb  = (const float*)d_in[46];

    float* outf = (float*)d_out;

    // ---- ws scratch (int offsets; cum/melint slots retained but unused) ----
    int*    cum    = (int*)d_ws;                    // 16384 (unused)
    int*    melint = cum + 16384;                   // 64    (unused)
    int*    idxp   = melint + 64;                   // 16384
    int*    idxe   = idxp + 16384;                  // 16384
    ushort* zp     = (ushort*)(idxe + 16384);       // 32 ushorts (16B-aligned)
    int*    tmap   = idxe + 16448;                  // 131072
    ushort* xob    = (ushort*)((float*)d_ws + 262144);  // Mv*512 bf16, 1MB offset

    // ---- d_out front scratch (float offsets; regulate overwrites all) ----
    #define OBUF(i) ((ushort*)(outf + (size_t)(i) * 4194304))
    uchar*  xb8 = (uchar*)OBUF(0);
    ushort* eb  = OBUF(1);
    ushort* pA0 = OBUF(2);   ushort* pA1 = OBUF(3);  ushort* pA2 = OBUF(4);
    uchar*  xp8 = (uchar*)OBUF(5);
    uchar*  xe8 = (uchar*)OBUF(6);
    uchar*  c8_0 = (uchar*)OBUF(7);
    uchar*  c8_1 = (uchar*)OBUF(8);
    uchar*  c8_2 = (uchar*)OBUF(9);
    float*  rss  = outf + 10ull * 4194304;          // 3*Mv
    float*  ss2  = rss + 3 * Mv;                    // 3*Mv
    float*  sgw  = rss + 6 * Mv;                    // 3*Mv
    uchar*  w8[6];
    ushort* wt[6];
    {
        size_t off = 13ull * 4194304;
        for (int i = 0; i < 6; ++i) { w8[i] = (uchar*)(outf + off); off += 196608; }  // conv 512x1536 fp8
        for (int i = 0; i < 6; ++i) { wt[i] = (ushort*)(outf + off); off += 131072; } // proj 512x512 bf16
    }

    hipMemsetAsync(zp, 0, 64, stream);
    hipMemsetAsync(rss, 0, 9ull * Mv * sizeof(float), stream);

    // converts + transposes
    convert_kernel<<<dim3(4096, 2), 256, 0, stream>>>(x, emb, xb8, eb);
    { TransArgs ta = {{dw1, dw2, pw1, pw2, ew1, ew2},
                      {nullptr, dg1, nullptr, pg1, nullptr, eg1},
                      {w8[0], w8[1], w8[2], w8[3], w8[4], w8[5]}};
      transpose_kernel<1><<<dim3(48, 16, 6), 256, 0, stream>>>(ta, 1536); }
    { TransArgs ta = {{ppw1, ppw2, epw1, epw2, spw1, spw2},
                      {nullptr, nullptr, nullptr, nullptr, nullptr, nullptr},
                      {wt[0], wt[1], wt[2], wt[3], wt[4], wt[5]}};
      transpose_kernel<0><<<dim3(16, 16, 6), 256, 0, stream>>>(ta, 512); }

    idx_kernel<<<Mv / 256, 256, 0, stream>>>(pt, et, pbins, ebins, idxp, idxe);
    cumtmap_kernel<<<Bv, Lv, 0, stream>>>(durt, outf + MEL_OFF, tmap);

    const dim3 g3(Fv / 128, Mv / 128, 3);   // (4, 128, 3) = 1536 blocks

    // proj1: h = relu(emb @ w1 + b1) for pp/ep/sp (bf16)
    { GArgs<3> a = {{eb, eb, eb}, {wt[0], wt[2], wt[4]}, {ppb1, epb1, spb1}, {pA0, pA1, pA2}};
      gemm_bf16_kernel<1, 0, 3><<<g3, 256, 0, stream>>>(a, nullptr, nullptr, nullptr,
                                                        nullptr, nullptr, zp); }
    // proj2 merged: z<2 -> x + relu(h@w2+b2) as FP8 (xp8/xe8); z==2 adds
    // pe+ee -> bf16 xob
    { GArgs<3> a = {{pA0, pA1, pA2}, {wt[1], wt[3], wt[5]}, {ppb2, epb2, spb2},
                    {(ushort*)xp8, (ushort*)xe8, xob}};
      gemm_bf16_kernel<1, 3, 3><<<g3, 256, 0, stream>>>(a, x, pemb, eemb,
                                                        idxp, idxe, zp); }

    // conv1 fp8 for {pit, eng, dur}: fp8 C + rss atomics (rms1 fold)
    { GArgs8<3> a = {{xp8, xe8, xb8}, {w8[2], w8[4], w8[0]}, {pb1, eb1, db1},
                     {c8_0, c8_1, c8_2}};
      EpiArgs ea = {rss, nullptr, nullptr, {nullptr, nullptr, nullptr},
                    {nullptr, nullptr, nullptr}};
      gemm_fp8_kernel<4, 3><<<g3, 256, 0, stream>>>(a, ea, (const uchar*)zp); }
    // conv2 fp8 (g1-folded weights): inv from rss inline; no C write;
    // ss2/sgw atomics (rmslin fold)
    { GArgs8<3> a = {{c8_0, c8_1, c8_2}, {w8[3], w8[5], w8[1]}, {pb2, eb2, db2},
                     {c8_0, c8_1, c8_2}};
      EpiArgs ea = {rss, ss2, sgw, {pg2, eg2, dg2}, {pwl, ewl, dwl}};
      gemm_fp8_kernel<5, 3><<<g3, 256, 0, stream>>>(a, ea, (const uchar*)zp); }
    // pred finalize -> preds at PIT|ENG|DUR (contiguous, z-ordered)
    pred_kernel<<<3 * Mv / 256, 256, 0, stream>>>(ss2, sgw, mask, pbl, ebl, dbl,
                                                  outf + PIT_OFF);

    // length regulate gather -> out (overwrites all d_out-front scratch)
    regulate_kernel<<<Bv * Tv, 128, 0, stream>>>(xob, tmap, outf + OUT_OFF);
}